// Round 2
// baseline (296.446 us; speedup 1.0000x reference)
//
#include <hip/hip_runtime.h>

// BTT(4096->4096, m=n=a=b=64, rank=8) == dense 4096x4096 matmul:
//   W[n*64+b][m*64+a] = sum_r R[n,b,m*8+r] * L[m,n*8+r,a];  out = x @ W + bias
// R6b: 256x256 tile, 8-wave, ring-of-8 K-slice pipeline with counted vmcnt
// (never 0 in main loop), setprio around MFMA clusters. Global layout is
// slice-major ([tile256][kslice16 x 256][rowblk32 x 8][lane64][8] bf16) so each
// 8KB slice stages as one linear global_load_lds per thread and ds_read_b128
// is conflict-free by construction (T2 via layout; SQ_LDS_BANK_CONFLICT==0).
// (Resubmission of R6 — previous round failed at container acquisition.)

typedef float f32x16 __attribute__((ext_vector_type(16)));
typedef short short8 __attribute__((ext_vector_type(8)));

static __device__ __forceinline__ unsigned short f2b(float f) {
    union { float f; unsigned u; } a; a.f = f;
    unsigned u = a.u;
    unsigned r = u + 0x7fffu + ((u >> 16) & 1u);   // RNE
    return (unsigned short)(r >> 16);
}

static __device__ __forceinline__ void load_lds_16(const void* gptr, void* lptr) {
    __builtin_amdgcn_global_load_lds(
        (const __attribute__((address_space(1))) unsigned int*)gptr,
        (__attribute__((address_space(3))) unsigned int*)lptr, 16, 0, 0);
}

// ---------------- merged prep: blocks [0,nx) convert x, blocks [nx,nx+4096) build W ----
// Slice-major dst: elem (row,k) -> rt=row>>8, ks=k>>4, rb=(row>>5)&7,
//                  lane=((k>>3)&1)*32+(row&31), j=k&7
//   index = (((rt*256 + ks)*8 + rb)*64 + lane)*8 + j
__global__ __launch_bounds__(256) void prep_all(
    const float* __restrict__ x,       // [4096][4096]
    const float* __restrict__ btt_r,   // [64][64][512]
    const float* __restrict__ btt_l,   // [64][512][64]
    unsigned short* __restrict__ xbt,  // tiled bf16
    unsigned short* __restrict__ Wtt,  // tiled bf16
    int nx)
{
    const int tid = threadIdx.x;
    if ((int)blockIdx.x < nx) {
        // ---- x conversion: 1 granule (8 elems) / thread; 8-row thread groups so
        // tiled writes coalesce into 128B lines.
        unsigned i = blockIdx.x * 256 + tid;
        int row = ((i >> 12) << 3) | (i & 7);
        int g   = (i >> 3) & 511;          // k-granule 0..511
        float4 v0 = *(const float4*)(x + (size_t)row * 4096 + g * 8);
        float4 v1 = *(const float4*)(x + (size_t)row * 4096 + g * 8 + 4);
        unsigned short o[8];
        o[0] = f2b(v0.x); o[1] = f2b(v0.y); o[2] = f2b(v0.z); o[3] = f2b(v0.w);
        o[4] = f2b(v1.x); o[5] = f2b(v1.y); o[6] = f2b(v1.z); o[7] = f2b(v1.w);
        int ks = g >> 1, half = g & 1;
        int rt = row >> 8, rb = (row >> 5) & 7, l31 = row & 31;
        size_t dst = ((((size_t)rt * 256 + ks) * 8 + rb) * 64 + half * 32 + l31) * 8;
        *(uint4*)(xbt + dst) = *(const uint4*)o;
        return;
    }
    // ---- W composition (per (m,n) block), slice-major dst
    __shared__ float Rs[64][8];
    __shared__ float Ls[8][64];
    const int wb = blockIdx.x - nx;
    const int m = wb >> 6, n = wb & 63;

    if (tid < 128) {
        int b = tid >> 1, rh = (tid & 1) * 4;
        float4 v = *(const float4*)(btt_r + (size_t)n * 32768 + (size_t)b * 512 + m * 8 + rh);
        *(float4*)&Rs[b][rh] = v;
    } else {
        int t2 = (tid - 128) * 4;
        float4 v = *(const float4*)(btt_l + (size_t)m * 32768 + n * 512 + t2);
        *(float4*)&(&Ls[0][0])[t2] = v;
    }
    __syncthreads();

    const int a  = tid >> 2;
    const int bg = (tid & 3) * 16;     // k-offset within n-block: 0,16,32,48
    float la[8];
    #pragma unroll
    for (int r = 0; r < 8; ++r) la[r] = Ls[r][a];

    unsigned short o[16];
    #pragma unroll
    for (int bb = 0; bb < 16; ++bb) {
        float acc = 0.f;
        #pragma unroll
        for (int r = 0; r < 8; ++r) acc += Rs[bg + bb][r] * la[r];
        o[bb] = f2b(acc);
    }
    // col = m*64+a (gemm "row" of W^T); k = n*64 + bg + t
    int col = m * 64 + a;
    int ct = col >> 8, rb = (col >> 5) & 7, l31 = col & 31;
    int ks = n * 4 + (bg >> 4);        // global 16-k slice index
    size_t dst = ((((size_t)ct * 256 + ks) * 8 + rb) * 64 + l31) * 8;
    *(uint4*)(Wtt + dst)           = *(const uint4*)&o[0];   // k-octet half 0
    *(uint4*)(Wtt + dst + 32 * 8)  = *(const uint4*)&o[8];   // k-octet half 1
}

// ---------------- gemm: 256x256 tile, 8 waves (2Mx4N), ring-of-8 16-K-slices --------
// Pipeline invariants (per wave, 2 loads per slice, 4 loads per 2-slice group):
//   prologue: stage slices 0..5; vmcnt(8)  => own slices 0,1 landed
//   group j (s0=2j): BARRIER   => with prev group's vmcnt(8), ALL waves' loads
//                                 through slice s0+1 have landed; also all waves
//                                 are done reading slices s0-2,s0-1 (slots of
//                                 s0+6,s0+7) so restage is WAR-safe.
//     stage s0+6,s0+7; vmcnt(8) => own loads through s0+3 landed (for group j+1)
//     compute slices s0,s0+1 (6 ds_read_b128 + 8 MFMA each, setprio-wrapped)
//   tail groups drain vmcnt 4 -> 0.
__global__ __launch_bounds__(512, 2) void gemm_btt(
    const unsigned short* __restrict__ xbt,  // tiled
    const unsigned short* __restrict__ Wtt,  // tiled
    const float* __restrict__ bias,
    float* __restrict__ out)
{
    __shared__ unsigned short As[8][4096];   // 8 slots x 8KB
    __shared__ unsigned short Bs[8][4096];   // 128KB total -> 1 block/CU

    const int tid = threadIdx.x;
    // XCD-aware swizzle (bijective, 256 blocks): XCD x gets rt in {2x,2x+1} x all ct
    const int bid = blockIdx.x;
    const int cpx = gridDim.x >> 3;          // 32
    const int swz = (bid & 7) * cpx + (bid >> 3);
    const int rt = swz >> 4;
    const int ct = swz & 15;

    const int wid = tid >> 6, l = tid & 63;
    const int l31 = l & 31, half = l >> 5;
    const int wr = wid >> 2;                 // 0..1: 128-row half
    const int wc = wid & 3;                  // 0..3: 64-col quarter

    const unsigned short* xa = xbt + (size_t)rt * (256 * 4096);
    const unsigned short* wa = Wtt + (size_t)ct * (256 * 4096);

    // per-thread LDS read offsets (shorts)
    const int offA0 = ((wr * 4 + 0) * 64 + l) * 8;
    const int offA1 = ((wr * 4 + 1) * 64 + l) * 8;
    const int offA2 = ((wr * 4 + 2) * 64 + l) * 8;
    const int offA3 = ((wr * 4 + 3) * 64 + l) * 8;
    const int offB0 = ((wc * 2 + 0) * 64 + l) * 8;
    const int offB1 = ((wc * 2 + 1) * 64 + l) * 8;

    f32x16 acc[4][2];
    #pragma unroll
    for (int i = 0; i < 4; ++i)
        #pragma unroll
        for (int j = 0; j < 2; ++j)
            #pragma unroll
            for (int r = 0; r < 16; ++r)
                acc[i][j][r] = 0.f;

    #define STAGE(s) do {                                                    \
        load_lds_16(xa + (size_t)(s) * 4096 + tid * 8, &As[(s) & 7][tid * 8]); \
        load_lds_16(wa + (size_t)(s) * 4096 + tid * 8, &Bs[(s) & 7][tid * 8]); \
    } while (0)

    #define BARRIER() do {                                                   \
        asm volatile("s_waitcnt lgkmcnt(0)" ::: "memory");                   \
        __builtin_amdgcn_s_barrier();                                        \
        asm volatile("" ::: "memory");                                       \
    } while (0)

    #define SLICE(s) do {                                                    \
        const unsigned short* Ab = &As[(s) & 7][0];                          \
        const unsigned short* Bb = &Bs[(s) & 7][0];                          \
        short8 af0 = *(const short8*)(Ab + offA0);                           \
        short8 af1 = *(const short8*)(Ab + offA1);                           \
        short8 af2 = *(const short8*)(Ab + offA2);                           \
        short8 af3 = *(const short8*)(Ab + offA3);                           \
        short8 bf0 = *(const short8*)(Bb + offB0);                           \
        short8 bf1 = *(const short8*)(Bb + offB1);                           \
        __builtin_amdgcn_s_setprio(1);                                       \
        acc[0][0] = __builtin_amdgcn_mfma_f32_32x32x16_bf16(af0, bf0, acc[0][0], 0, 0, 0); \
        acc[0][1] = __builtin_amdgcn_mfma_f32_32x32x16_bf16(af0, bf1, acc[0][1], 0, 0, 0); \
        acc[1][0] = __builtin_amdgcn_mfma_f32_32x32x16_bf16(af1, bf0, acc[1][0], 0, 0, 0); \
        acc[1][1] = __builtin_amdgcn_mfma_f32_32x32x16_bf16(af1, bf1, acc[1][1], 0, 0, 0); \
        acc[2][0] = __builtin_amdgcn_mfma_f32_32x32x16_bf16(af2, bf0, acc[2][0], 0, 0, 0); \
        acc[2][1] = __builtin_amdgcn_mfma_f32_32x32x16_bf16(af2, bf1, acc[2][1], 0, 0, 0); \
        acc[3][0] = __builtin_amdgcn_mfma_f32_32x32x16_bf16(af3, bf0, acc[3][0], 0, 0, 0); \
        acc[3][1] = __builtin_amdgcn_mfma_f32_32x32x16_bf16(af3, bf1, acc[3][1], 0, 0, 0); \
        __builtin_amdgcn_s_setprio(0);                                       \
    } while (0)

    // prologue: 6 slices in flight
    #pragma unroll
    for (int s = 0; s < 6; ++s) STAGE(s);
    asm volatile("s_waitcnt vmcnt(8)" ::: "memory");

    #pragma unroll 1
    for (int j = 0; j < 125; ++j) {
        const int s0 = 2 * j;
        BARRIER();
        STAGE(s0 + 6);
        STAGE(s0 + 7);
        asm volatile("s_waitcnt vmcnt(8)" ::: "memory");
        SLICE(s0);
        SLICE(s0 + 1);
    }
    // tail: drain counted waits 4 -> 0
    BARRIER();
    asm volatile("s_waitcnt vmcnt(4)" ::: "memory");
    SLICE(250);
    SLICE(251);
    BARRIER();
    asm volatile("s_waitcnt vmcnt(0)" ::: "memory");
    SLICE(252);
    SLICE(253);
    BARRIER();
    SLICE(254);
    SLICE(255);

    // epilogue: C/D layout col=lane&31, row=(r&3)+8*(r>>2)+4*half  [m74/m101]
    const int rowTileBase = rt * 256 + wr * 128;
    const int colTileBase = ct * 256 + wc * 64;
    #pragma unroll
    for (int jn = 0; jn < 2; ++jn) {
        const int col = colTileBase + jn * 32 + l31;
        const float bv = bias[col];
        #pragma unroll
        for (int i = 0; i < 4; ++i) {
            const int rbase = rowTileBase + i * 32 + 4 * half;
            #pragma unroll
            for (int r = 0; r < 16; ++r) {
                int row = rbase + (r & 3) + 8 * (r >> 2);
                out[(size_t)row * 4096 + col] = acc[i][jn][r] + bv;
            }
        }
    }
    #undef STAGE
    #undef BARRIER
    #undef SLICE
}

extern "C" void kernel_launch(void* const* d_in, const int* in_sizes, int n_in,
                              void* d_out, int out_size, void* d_ws, size_t ws_size,
                              hipStream_t stream) {
    const float* x    = (const float*)d_in[0];
    const float* r    = (const float*)d_in[1];
    const float* l    = (const float*)d_in[2];
    const float* bias = (const float*)d_in[3];
    float* out = (float*)d_out;

    unsigned short* xbt = (unsigned short*)d_ws;                       // 32 MB
    unsigned short* Wtt = (unsigned short*)d_ws + (size_t)4096 * 4096; // 32 MB

    const int rows = in_sizes[0] / 4096;        // 4096
    const int nx = rows * 4096 / 8 / 256;       // 8192 x-conversion blocks

    prep_all<<<dim3(nx + 4096), dim3(256), 0, stream>>>(x, r, l, xbt, Wtt, nx);
    gemm_btt<<<dim3((rows / 256) * 16), dim3(512), 0, stream>>>(xbt, Wtt, bias, out);
}

// Round 3
// 281.798 us; speedup vs baseline: 1.0520x; 1.0520x over previous
//
#include <hip/hip_runtime.h>

// BTT(4096->4096, m=n=a=b=64, rank=8) == dense 4096x4096 matmul:
//   W[n*64+b][m*64+a] = sum_r R[n,b,m*8+r] * L[m,n*8+r,a];  out = x @ W + bias
// R7: faithful m201-style 8-phase schedule on a ring of 8 16-k slices.
// Per phase: {6 ds_read_b128 ; stage slice s+4 (2 global_load_lds) ; vmcnt(6) ;
// barrier ; lgkmcnt(0) ; setprio(1) ; 8 MFMA 32x32x16 ; setprio(0) ; barrier}.
// vmcnt never 0 in main loop (T4); T5 setprio; T2 via fragment-major layout
// (SQ_LDS_BANK_CONFLICT==0). Rect 4rtx8ct XCD swizzle (T1).

typedef float f32x16 __attribute__((ext_vector_type(16)));
typedef short short8 __attribute__((ext_vector_type(8)));

static __device__ __forceinline__ unsigned short f2b(float f) {
    union { float f; unsigned u; } a; a.f = f;
    unsigned u = a.u;
    unsigned r = u + 0x7fffu + ((u >> 16) & 1u);   // RNE
    return (unsigned short)(r >> 16);
}

static __device__ __forceinline__ void load_lds_16(const void* gptr, void* lptr) {
    __builtin_amdgcn_global_load_lds(
        (const __attribute__((address_space(1))) unsigned int*)gptr,
        (__attribute__((address_space(3))) unsigned int*)lptr, 16, 0, 0);
}

// ---------------- merged prep: blocks [0,nx) convert x, blocks [nx,nx+4096) build W ----
// Slice-major dst: elem (row,k) -> rt=row>>8, ks=k>>4, rb=(row>>5)&7,
//                  lane=((k>>3)&1)*32+(row&31), j=k&7
//   index = (((rt*256 + ks)*8 + rb)*64 + lane)*8 + j
__global__ __launch_bounds__(256) void prep_all(
    const float* __restrict__ x,       // [4096][4096]
    const float* __restrict__ btt_r,   // [64][64][512]
    const float* __restrict__ btt_l,   // [64][512][64]
    unsigned short* __restrict__ xbt,  // tiled bf16
    unsigned short* __restrict__ Wtt,  // tiled bf16
    int nx)
{
    const int tid = threadIdx.x;
    if ((int)blockIdx.x < nx) {
        unsigned i = blockIdx.x * 256 + tid;
        int row = ((i >> 12) << 3) | (i & 7);
        int g   = (i >> 3) & 511;          // k-granule 0..511
        float4 v0 = *(const float4*)(x + (size_t)row * 4096 + g * 8);
        float4 v1 = *(const float4*)(x + (size_t)row * 4096 + g * 8 + 4);
        unsigned short o[8];
        o[0] = f2b(v0.x); o[1] = f2b(v0.y); o[2] = f2b(v0.z); o[3] = f2b(v0.w);
        o[4] = f2b(v1.x); o[5] = f2b(v1.y); o[6] = f2b(v1.z); o[7] = f2b(v1.w);
        int ks = g >> 1, half = g & 1;
        int rt = row >> 8, rb = (row >> 5) & 7, l31 = row & 31;
        size_t dst = ((((size_t)rt * 256 + ks) * 8 + rb) * 64 + half * 32 + l31) * 8;
        *(uint4*)(xbt + dst) = *(const uint4*)o;
        return;
    }
    // ---- W composition (per (m,n) block), slice-major dst
    __shared__ float Rs[64][8];
    __shared__ float Ls[8][64];
    const int wb = blockIdx.x - nx;
    const int m = wb >> 6, n = wb & 63;

    if (tid < 128) {
        int b = tid >> 1, rh = (tid & 1) * 4;
        float4 v = *(const float4*)(btt_r + (size_t)n * 32768 + (size_t)b * 512 + m * 8 + rh);
        *(float4*)&Rs[b][rh] = v;
    } else {
        int t2 = (tid - 128) * 4;
        float4 v = *(const float4*)(btt_l + (size_t)m * 32768 + n * 512 + t2);
        *(float4*)&(&Ls[0][0])[t2] = v;
    }
    __syncthreads();

    const int a  = tid >> 2;
    const int bg = (tid & 3) * 16;     // k-offset within n-block: 0,16,32,48
    float la[8];
    #pragma unroll
    for (int r = 0; r < 8; ++r) la[r] = Ls[r][a];

    unsigned short o[16];
    #pragma unroll
    for (int bb = 0; bb < 16; ++bb) {
        float acc = 0.f;
        #pragma unroll
        for (int r = 0; r < 8; ++r) acc += Rs[bg + bb][r] * la[r];
        o[bb] = f2b(acc);
    }
    int col = m * 64 + a;
    int ct = col >> 8, rb = (col >> 5) & 7, l31 = col & 31;
    int ks = n * 4 + (bg >> 4);        // global 16-k slice index
    size_t dst = ((((size_t)ct * 256 + ks) * 8 + rb) * 64 + l31) * 8;
    *(uint4*)(Wtt + dst)           = *(const uint4*)&o[0];   // k-octet half 0
    *(uint4*)(Wtt + dst + 32 * 8)  = *(const uint4*)&o[8];   // k-octet half 1
}

// ---------------- gemm: 256x256 tile, 8 waves (2Mx4N), 8-phase ring-of-8 ------------
__global__ __launch_bounds__(512, 2) void gemm_btt(
    const unsigned short* __restrict__ xbt,  // tiled
    const unsigned short* __restrict__ Wtt,  // tiled
    const float* __restrict__ bias,
    float* __restrict__ out)
{
    __shared__ unsigned short As[8][4096];   // 8 slots x 8KB
    __shared__ unsigned short Bs[8][4096];   // 128KB total -> 1 block/CU

    const int tid = threadIdx.x;
    // XCD rect swizzle: XCD x owns a 4rt x 8ct rectangle (bijective over 256 blocks)
    const int bid = blockIdx.x;
    const int jj = bid >> 3, xc = bid & 7;
    const int rt = (xc >> 1) * 4 + (jj >> 3);
    const int ct = (xc & 1) * 8 + (jj & 7);

    const int wid = tid >> 6, l = tid & 63;
    const int l31 = l & 31, half = l >> 5;
    const int wr = wid >> 2;                 // 0..1: 128-row half
    const int wc = wid & 3;                  // 0..3: 64-col quarter

    const unsigned short* xa = xbt + (size_t)rt * (256 * 4096);
    const unsigned short* wa = Wtt + (size_t)ct * (256 * 4096);

    const int offA0 = ((wr * 4 + 0) * 64 + l) * 8;
    const int offA1 = ((wr * 4 + 1) * 64 + l) * 8;
    const int offA2 = ((wr * 4 + 2) * 64 + l) * 8;
    const int offA3 = ((wr * 4 + 3) * 64 + l) * 8;
    const int offB0 = ((wc * 2 + 0) * 64 + l) * 8;
    const int offB1 = ((wc * 2 + 1) * 64 + l) * 8;

    f32x16 acc[4][2];
    #pragma unroll
    for (int i = 0; i < 4; ++i)
        #pragma unroll
        for (int j = 0; j < 2; ++j)
            #pragma unroll
            for (int r = 0; r < 16; ++r)
                acc[i][j][r] = 0.f;

    #define STAGE(s, slot) do {                                               \
        load_lds_16(xa + (size_t)(s) * 4096 + tid * 8, &As[slot][tid * 8]);   \
        load_lds_16(wa + (size_t)(s) * 4096 + tid * 8, &Bs[slot][tid * 8]);   \
    } while (0)

    // one phase: ds-reads ; STAGE_STMT ; vmcnt ; barrier ; lgkm(0) ; 8 MFMA ; barrier
    #define PHASE(slot, STAGE_STMT, VMSTR) do {                               \
        const unsigned short* Ab = &As[slot][0];                              \
        const unsigned short* Bb = &Bs[slot][0];                              \
        short8 af0 = *(const short8*)(Ab + offA0);                            \
        short8 af1 = *(const short8*)(Ab + offA1);                            \
        short8 af2 = *(const short8*)(Ab + offA2);                            \
        short8 af3 = *(const short8*)(Ab + offA3);                            \
        short8 bf0 = *(const short8*)(Bb + offB0);                            \
        short8 bf1 = *(const short8*)(Bb + offB1);                            \
        STAGE_STMT;                                                           \
        asm volatile(VMSTR ::: "memory");                                     \
        __builtin_amdgcn_s_barrier();                                         \
        asm volatile("s_waitcnt lgkmcnt(0)" ::: "memory");                    \
        __builtin_amdgcn_s_setprio(1);                                        \
        acc[0][0] = __builtin_amdgcn_mfma_f32_32x32x16_bf16(af0, bf0, acc[0][0], 0, 0, 0); \
        acc[0][1] = __builtin_amdgcn_mfma_f32_32x32x16_bf16(af0, bf1, acc[0][1], 0, 0, 0); \
        acc[1][0] = __builtin_amdgcn_mfma_f32_32x32x16_bf16(af1, bf0, acc[1][0], 0, 0, 0); \
        acc[1][1] = __builtin_amdgcn_mfma_f32_32x32x16_bf16(af1, bf1, acc[1][1], 0, 0, 0); \
        acc[2][0] = __builtin_amdgcn_mfma_f32_32x32x16_bf16(af2, bf0, acc[2][0], 0, 0, 0); \
        acc[2][1] = __builtin_amdgcn_mfma_f32_32x32x16_bf16(af2, bf1, acc[2][1], 0, 0, 0); \
        acc[3][0] = __builtin_amdgcn_mfma_f32_32x32x16_bf16(af3, bf0, acc[3][0], 0, 0, 0); \
        acc[3][1] = __builtin_amdgcn_mfma_f32_32x32x16_bf16(af3, bf1, acc[3][1], 0, 0, 0); \
        __builtin_amdgcn_s_setprio(0);                                        \
        __builtin_amdgcn_s_barrier();                                         \
        asm volatile("" ::: "memory");                                        \
    } while (0)

    // prologue: stage slices 0..3; own slice-0 loads done; all waves synced
    STAGE(0, 0); STAGE(1, 1); STAGE(2, 2); STAGE(3, 3);
    asm volatile("s_waitcnt vmcnt(6)" ::: "memory");
    __builtin_amdgcn_s_barrier();
    asm volatile("" ::: "memory");

    // main: phases s = 0..247 (31 iters x 8 phases), stage slice s+4, vmcnt(6)
    #pragma unroll 1
    for (int it = 0; it < 31; ++it) {
        const int s0 = it * 8;
        PHASE(0, STAGE(s0 + 4,  4), "s_waitcnt vmcnt(6)");
        PHASE(1, STAGE(s0 + 5,  5), "s_waitcnt vmcnt(6)");
        PHASE(2, STAGE(s0 + 6,  6), "s_waitcnt vmcnt(6)");
        PHASE(3, STAGE(s0 + 7,  7), "s_waitcnt vmcnt(6)");
        PHASE(4, STAGE(s0 + 8,  0), "s_waitcnt vmcnt(6)");
        PHASE(5, STAGE(s0 + 9,  1), "s_waitcnt vmcnt(6)");
        PHASE(6, STAGE(s0 + 10, 2), "s_waitcnt vmcnt(6)");
        PHASE(7, STAGE(s0 + 11, 3), "s_waitcnt vmcnt(6)");
    }
    // tail: phases 248..255; last stages 252..255, then drain 6->4->2->0
    PHASE(0, STAGE(252, 4), "s_waitcnt vmcnt(6)");
    PHASE(1, STAGE(253, 5), "s_waitcnt vmcnt(6)");
    PHASE(2, STAGE(254, 6), "s_waitcnt vmcnt(6)");
    PHASE(3, STAGE(255, 7), "s_waitcnt vmcnt(6)");
    PHASE(4, ((void)0),     "s_waitcnt vmcnt(4)");
    PHASE(5, ((void)0),     "s_waitcnt vmcnt(2)");
    PHASE(6, ((void)0),     "s_waitcnt vmcnt(0)");
    PHASE(7, ((void)0),     "s_waitcnt vmcnt(0)");

    // epilogue: C/D layout col=lane&31, row=(r&3)+8*(r>>2)+4*half  [m74/m101]
    const int rowTileBase = rt * 256 + wr * 128;
    const int colTileBase = ct * 256 + wc * 64;
    #pragma unroll
    for (int jn = 0; jn < 2; ++jn) {
        const int col = colTileBase + jn * 32 + l31;
        const float bv = bias[col];
        #pragma unroll
        for (int i = 0; i < 4; ++i) {
            const int rbase = rowTileBase + i * 32 + 4 * half;
            #pragma unroll
            for (int r = 0; r < 16; ++r) {
                int row = rbase + (r & 3) + 8 * (r >> 2);
                out[(size_t)row * 4096 + col] = acc[i][jn][r] + bv;
            }
        }
    }
    #undef STAGE
    #undef PHASE
}

extern "C" void kernel_launch(void* const* d_in, const int* in_sizes, int n_in,
                              void* d_out, int out_size, void* d_ws, size_t ws_size,
                              hipStream_t stream) {
    const float* x    = (const float*)d_in[0];
    const float* r    = (const float*)d_in[1];
    const float* l    = (const float*)d_in[2];
    const float* bias = (const float*)d_in[3];
    float* out = (float*)d_out;

    unsigned short* xbt = (unsigned short*)d_ws;                       // 32 MB
    unsigned short* Wtt = (unsigned short*)d_ws + (size_t)4096 * 4096; // 32 MB

    const int rows = in_sizes[0] / 4096;        // 4096
    const int nx = rows * 4096 / 8 / 256;       // 8192 x-conversion blocks

    prep_all<<<dim3(nx + 4096), dim3(256), 0, stream>>>(x, r, l, xbt, Wtt, nx);
    gemm_btt<<<dim3((rows / 256) * 16), dim3(512), 0, stream>>>(xbt, Wtt, bias, out);
}

// Round 4
// 280.523 us; speedup vs baseline: 1.0568x; 1.0045x over previous
//
#include <hip/hip_runtime.h>

// BTT(4096->4096, m=n=a=b=64, rank=8) == dense 4096x4096 matmul:
//   W[n*64+b][m*64+a] = sum_r R[n,b,m*8+r] * L[m,n*8+r,a];  out = x @ W + bias
// R8: single-barrier phases with one-phase-ahead fragment prefetch.
// Phase s: {stage slice s+4 ; vmcnt(6) ; barrier ; ds_read frags[s+1] ;
//           8 MFMA on frags[s] (overlaps LDS service of the new reads)}.
// vmcnt never 0 in main loop (T4); setprio (T5); conflict-free fragment-major
// LDS layout (T2-by-construction); rect 4x8 XCD swizzle (T1).
// Safety: RAW on slot s+1 = all-waves vmcnt(6) + barrier; WAR on restaged slot
// (s+4)&7 = readers' lgkm wait at phase s-4 + 4 intervening barriers.

typedef float f32x16 __attribute__((ext_vector_type(16)));
typedef short short8 __attribute__((ext_vector_type(8)));

static __device__ __forceinline__ unsigned short f2b(float f) {
    union { float f; unsigned u; } a; a.f = f;
    unsigned u = a.u;
    unsigned r = u + 0x7fffu + ((u >> 16) & 1u);   // RNE
    return (unsigned short)(r >> 16);
}

static __device__ __forceinline__ void load_lds_16(const void* gptr, void* lptr) {
    __builtin_amdgcn_global_load_lds(
        (const __attribute__((address_space(1))) unsigned int*)gptr,
        (__attribute__((address_space(3))) unsigned int*)lptr, 16, 0, 0);
}

// ---------------- merged prep: blocks [0,nx) convert x, blocks [nx,nx+4096) build W ----
// Slice-major dst: elem (row,k) -> rt=row>>8, ks=k>>4, rb=(row>>5)&7,
//                  lane=((k>>3)&1)*32+(row&31), j=k&7
//   index = (((rt*256 + ks)*8 + rb)*64 + lane)*8 + j
__global__ __launch_bounds__(256) void prep_all(
    const float* __restrict__ x,       // [4096][4096]
    const float* __restrict__ btt_r,   // [64][64][512]
    const float* __restrict__ btt_l,   // [64][512][64]
    unsigned short* __restrict__ xbt,  // tiled bf16
    unsigned short* __restrict__ Wtt,  // tiled bf16
    int nx)
{
    const int tid = threadIdx.x;
    if ((int)blockIdx.x < nx) {
        unsigned i = blockIdx.x * 256 + tid;
        int row = ((i >> 12) << 3) | (i & 7);
        int g   = (i >> 3) & 511;          // k-granule 0..511
        float4 v0 = *(const float4*)(x + (size_t)row * 4096 + g * 8);
        float4 v1 = *(const float4*)(x + (size_t)row * 4096 + g * 8 + 4);
        unsigned short o[8];
        o[0] = f2b(v0.x); o[1] = f2b(v0.y); o[2] = f2b(v0.z); o[3] = f2b(v0.w);
        o[4] = f2b(v1.x); o[5] = f2b(v1.y); o[6] = f2b(v1.z); o[7] = f2b(v1.w);
        int ks = g >> 1, half = g & 1;
        int rt = row >> 8, rb = (row >> 5) & 7, l31 = row & 31;
        size_t dst = ((((size_t)rt * 256 + ks) * 8 + rb) * 64 + half * 32 + l31) * 8;
        *(uint4*)(xbt + dst) = *(const uint4*)o;
        return;
    }
    // ---- W composition (per (m,n) block), slice-major dst
    __shared__ float Rs[64][8];
    __shared__ float Ls[8][64];
    const int wb = blockIdx.x - nx;
    const int m = wb >> 6, n = wb & 63;

    if (tid < 128) {
        int b = tid >> 1, rh = (tid & 1) * 4;
        float4 v = *(const float4*)(btt_r + (size_t)n * 32768 + (size_t)b * 512 + m * 8 + rh);
        *(float4*)&Rs[b][rh] = v;
    } else {
        int t2 = (tid - 128) * 4;
        float4 v = *(const float4*)(btt_l + (size_t)m * 32768 + n * 512 + t2);
        *(float4*)&(&Ls[0][0])[t2] = v;
    }
    __syncthreads();

    const int a  = tid >> 2;
    const int bg = (tid & 3) * 16;     // k-offset within n-block: 0,16,32,48
    float la[8];
    #pragma unroll
    for (int r = 0; r < 8; ++r) la[r] = Ls[r][a];

    unsigned short o[16];
    #pragma unroll
    for (int bb = 0; bb < 16; ++bb) {
        float acc = 0.f;
        #pragma unroll
        for (int r = 0; r < 8; ++r) acc += Rs[bg + bb][r] * la[r];
        o[bb] = f2b(acc);
    }
    int col = m * 64 + a;
    int ct = col >> 8, rb = (col >> 5) & 7, l31 = col & 31;
    int ks = n * 4 + (bg >> 4);        // global 16-k slice index
    size_t dst = ((((size_t)ct * 256 + ks) * 8 + rb) * 64 + l31) * 8;
    *(uint4*)(Wtt + dst)           = *(const uint4*)&o[0];   // k-octet half 0
    *(uint4*)(Wtt + dst + 32 * 8)  = *(const uint4*)&o[8];   // k-octet half 1
}

// ---------------- gemm: 256x256 tile, 8 waves (2Mx4N), 1-barrier pipelined phases ----
__global__ __launch_bounds__(512, 2) void gemm_btt(
    const unsigned short* __restrict__ xbt,  // tiled
    const unsigned short* __restrict__ Wtt,  // tiled
    const float* __restrict__ bias,
    float* __restrict__ out)
{
    __shared__ unsigned short As[8][4096];   // 8 slots x 8KB
    __shared__ unsigned short Bs[8][4096];   // 128KB total -> 1 block/CU

    const int tid = threadIdx.x;
    // XCD rect swizzle: XCD x owns a 4rt x 8ct rectangle (bijective over 256 blocks)
    const int bid = blockIdx.x;
    const int jj = bid >> 3, xc = bid & 7;
    const int rt = (xc >> 1) * 4 + (jj >> 3);
    const int ct = (xc & 1) * 8 + (jj & 7);

    const int wid = tid >> 6, l = tid & 63;
    const int l31 = l & 31, half = l >> 5;
    const int wr = wid >> 2;                 // 0..1: 128-row half
    const int wc = wid & 3;                  // 0..3: 64-col quarter

    const unsigned short* xa = xbt + (size_t)rt * (256 * 4096);
    const unsigned short* wa = Wtt + (size_t)ct * (256 * 4096);

    const int offA0 = ((wr * 4 + 0) * 64 + l) * 8;
    const int offA1 = ((wr * 4 + 1) * 64 + l) * 8;
    const int offA2 = ((wr * 4 + 2) * 64 + l) * 8;
    const int offA3 = ((wr * 4 + 3) * 64 + l) * 8;
    const int offB0 = ((wc * 2 + 0) * 64 + l) * 8;
    const int offB1 = ((wc * 2 + 1) * 64 + l) * 8;

    f32x16 acc[4][2];
    #pragma unroll
    for (int i = 0; i < 4; ++i)
        #pragma unroll
        for (int j = 0; j < 2; ++j)
            #pragma unroll
            for (int r = 0; r < 16; ++r)
                acc[i][j][r] = 0.f;

    // fragment double-buffers (statically named — rule #20)
    short8 fA0, fA1, fA2, fA3, fB0, fB1;
    short8 gA0, gA1, gA2, gA3, gB0, gB1;

    #define STAGE(s, slot) do {                                               \
        load_lds_16(xa + (size_t)(s) * 4096 + tid * 8, &As[slot][tid * 8]);   \
        load_lds_16(wa + (size_t)(s) * 4096 + tid * 8, &Bs[slot][tid * 8]);   \
    } while (0)

    #define READ6(pA0,pA1,pA2,pA3,pB0,pB1, slot) do {                         \
        const unsigned short* Ab = &As[slot][0];                              \
        const unsigned short* Bb = &Bs[slot][0];                              \
        pA0 = *(const short8*)(Ab + offA0);                                   \
        pA1 = *(const short8*)(Ab + offA1);                                   \
        pA2 = *(const short8*)(Ab + offA2);                                   \
        pA3 = *(const short8*)(Ab + offA3);                                   \
        pB0 = *(const short8*)(Bb + offB0);                                   \
        pB1 = *(const short8*)(Bb + offB1);                                   \
    } while (0)

    #define MFMA8(cA0,cA1,cA2,cA3,cB0,cB1) do {                               \
        __builtin_amdgcn_s_setprio(1);                                        \
        acc[0][0] = __builtin_amdgcn_mfma_f32_32x32x16_bf16(cA0, cB0, acc[0][0], 0, 0, 0); \
        acc[0][1] = __builtin_amdgcn_mfma_f32_32x32x16_bf16(cA0, cB1, acc[0][1], 0, 0, 0); \
        acc[1][0] = __builtin_amdgcn_mfma_f32_32x32x16_bf16(cA1, cB0, acc[1][0], 0, 0, 0); \
        acc[1][1] = __builtin_amdgcn_mfma_f32_32x32x16_bf16(cA1, cB1, acc[1][1], 0, 0, 0); \
        acc[2][0] = __builtin_amdgcn_mfma_f32_32x32x16_bf16(cA2, cB0, acc[2][0], 0, 0, 0); \
        acc[2][1] = __builtin_amdgcn_mfma_f32_32x32x16_bf16(cA2, cB1, acc[2][1], 0, 0, 0); \
        acc[3][0] = __builtin_amdgcn_mfma_f32_32x32x16_bf16(cA3, cB0, acc[3][0], 0, 0, 0); \
        acc[3][1] = __builtin_amdgcn_mfma_f32_32x32x16_bf16(cA3, cB1, acc[3][1], 0, 0, 0); \
        __builtin_amdgcn_s_setprio(0);                                        \
    } while (0)

    // phase: stage ; counted vmcnt ; barrier ; read next frags ; MFMA current frags
    #define PHASE(STAGE_STMT, VMSTR, rslot, pA0,pA1,pA2,pA3,pB0,pB1, cA0,cA1,cA2,cA3,cB0,cB1) do { \
        STAGE_STMT;                                                           \
        asm volatile(VMSTR ::: "memory");                                     \
        __builtin_amdgcn_s_barrier();                                         \
        asm volatile("" ::: "memory");                                        \
        READ6(pA0,pA1,pA2,pA3,pB0,pB1, rslot);                                \
        MFMA8(cA0,cA1,cA2,cA3,cB0,cB1);                                       \
    } while (0)

    // prologue: stage slices 0..3; own slice-0 landed; synced; frags[0] -> f
    STAGE(0, 0); STAGE(1, 1); STAGE(2, 2); STAGE(3, 3);
    asm volatile("s_waitcnt vmcnt(6)" ::: "memory");
    __builtin_amdgcn_s_barrier();
    asm volatile("" ::: "memory");
    READ6(fA0, fA1, fA2, fA3, fB0, fB1, 0);

    // main: phases 0..247 (31 x 8); slot of phase s is s&7 (s0 multiple of 8)
    #pragma unroll 1
    for (int it = 0; it < 31; ++it) {
        const int s0 = it * 8;
        PHASE(STAGE(s0 + 4,  4), "s_waitcnt vmcnt(6)", 1, gA0,gA1,gA2,gA3,gB0,gB1, fA0,fA1,fA2,fA3,fB0,fB1);
        PHASE(STAGE(s0 + 5,  5), "s_waitcnt vmcnt(6)", 2, fA0,fA1,fA2,fA3,fB0,fB1, gA0,gA1,gA2,gA3,gB0,gB1);
        PHASE(STAGE(s0 + 6,  6), "s_waitcnt vmcnt(6)", 3, gA0,gA1,gA2,gA3,gB0,gB1, fA0,fA1,fA2,fA3,fB0,fB1);
        PHASE(STAGE(s0 + 7,  7), "s_waitcnt vmcnt(6)", 4, fA0,fA1,fA2,fA3,fB0,fB1, gA0,gA1,gA2,gA3,gB0,gB1);
        PHASE(STAGE(s0 + 8,  0), "s_waitcnt vmcnt(6)", 5, gA0,gA1,gA2,gA3,gB0,gB1, fA0,fA1,fA2,fA3,fB0,fB1);
        PHASE(STAGE(s0 + 9,  1), "s_waitcnt vmcnt(6)", 6, fA0,fA1,fA2,fA3,fB0,fB1, gA0,gA1,gA2,gA3,gB0,gB1);
        PHASE(STAGE(s0 + 10, 2), "s_waitcnt vmcnt(6)", 7, gA0,gA1,gA2,gA3,gB0,gB1, fA0,fA1,fA2,fA3,fB0,fB1);
        PHASE(STAGE(s0 + 11, 3), "s_waitcnt vmcnt(6)", 0, fA0,fA1,fA2,fA3,fB0,fB1, gA0,gA1,gA2,gA3,gB0,gB1);
    }
    // tail: phases 248..255; stages 252..255 then drain 6->4->2->0
    PHASE(STAGE(252, 4), "s_waitcnt vmcnt(6)", 1, gA0,gA1,gA2,gA3,gB0,gB1, fA0,fA1,fA2,fA3,fB0,fB1);  // 248
    PHASE(STAGE(253, 5), "s_waitcnt vmcnt(6)", 2, fA0,fA1,fA2,fA3,fB0,fB1, gA0,gA1,gA2,gA3,gB0,gB1);  // 249
    PHASE(STAGE(254, 6), "s_waitcnt vmcnt(6)", 3, gA0,gA1,gA2,gA3,gB0,gB1, fA0,fA1,fA2,fA3,fB0,fB1);  // 250
    PHASE(STAGE(255, 7), "s_waitcnt vmcnt(6)", 4, fA0,fA1,fA2,fA3,fB0,fB1, gA0,gA1,gA2,gA3,gB0,gB1);  // 251
    PHASE(((void)0),     "s_waitcnt vmcnt(4)", 5, gA0,gA1,gA2,gA3,gB0,gB1, fA0,fA1,fA2,fA3,fB0,fB1);  // 252
    PHASE(((void)0),     "s_waitcnt vmcnt(2)", 6, fA0,fA1,fA2,fA3,fB0,fB1, gA0,gA1,gA2,gA3,gB0,gB1);  // 253
    PHASE(((void)0),     "s_waitcnt vmcnt(0)", 7, gA0,gA1,gA2,gA3,gB0,gB1, fA0,fA1,fA2,fA3,fB0,fB1);  // 254
    MFMA8(gA0, gA1, gA2, gA3, gB0, gB1);                                                              // 255

    // epilogue: C/D layout col=lane&31, row=(r&3)+8*(r>>2)+4*half  [m74/m101]
    const int rowTileBase = rt * 256 + wr * 128;
    const int colTileBase = ct * 256 + wc * 64;
    #pragma unroll
    for (int jn = 0; jn < 2; ++jn) {
        const int col = colTileBase + jn * 32 + l31;
        const float bv = bias[col];
        #pragma unroll
        for (int i = 0; i < 4; ++i) {
            const int rbase = rowTileBase + i * 32 + 4 * half;
            #pragma unroll
            for (int r = 0; r < 16; ++r) {
                int row = rbase + (r & 3) + 8 * (r >> 2);
                out[(size_t)row * 4096 + col] = acc[i][jn][r] + bv;
            }
        }
    }
    #undef STAGE
    #undef READ6
    #undef MFMA8
    #undef PHASE
}

extern "C" void kernel_launch(void* const* d_in, const int* in_sizes, int n_in,
                              void* d_out, int out_size, void* d_ws, size_t ws_size,
                              hipStream_t stream) {
    const float* x    = (const float*)d_in[0];
    const float* r    = (const float*)d_in[1];
    const float* l    = (const float*)d_in[2];
    const float* bias = (const float*)d_in[3];
    float* out = (float*)d_out;

    unsigned short* xbt = (unsigned short*)d_ws;                       // 32 MB
    unsigned short* Wtt = (unsigned short*)d_ws + (size_t)4096 * 4096; // 32 MB

    const int rows = in_sizes[0] / 4096;        // 4096
    const int nx = rows * 4096 / 8 / 256;       // 8192 x-conversion blocks

    prep_all<<<dim3(nx + 4096), dim3(256), 0, stream>>>(x, r, l, xbt, Wtt, nx);
    gemm_btt<<<dim3((rows / 256) * 16), dim3(512), 0, stream>>>(xbt, Wtt, bias, out);
}

// Round 6
// 278.616 us; speedup vs baseline: 1.0640x; 1.0068x over previous
//
#include <hip/hip_runtime.h>

// BTT(4096->4096, m=n=a=b=64, rank=8) == dense 4096x4096 matmul:
//   W[n*64+b][m*64+a] = sum_r R[n,b,m*8+r] * L[m,n*8+r,a];  out = x @ W + bias
// R9b: 2-slice superphases (32 k per barrier). Per superphase:
//   {vmcnt(8) ; barrier ; stage slices s+6,s+7 ; ds_read 12 frags (slices s,s+1) ;
//    16 MFMA (slice-B reads overlap slice-A MFMAs via compiler lgkmcnt)}.
// 128 barriers/block (half of R8), 12 in-flight loads/wave. vmcnt never 0 until
// tail (T4); setprio (T5); conflict-free fragment-major LDS (T2); rect XCD swz (T1).
// (R9 failed to compile: STAGE statements in a comma-expression; fixed via STAGE2.)
// Safety: RAW = vmcnt(8) forces 4 oldest = slices s,s+1 (staged 3 sps ago);
// WAR = restage of slot (s+6)&7 is after barrier p; its readers' ds_reads
// completed before they crossed barrier p (reads feed MFMAs issued pre-barrier).

typedef float f32x16 __attribute__((ext_vector_type(16)));
typedef short short8 __attribute__((ext_vector_type(8)));

static __device__ __forceinline__ unsigned short f2b(float f) {
    union { float f; unsigned u; } a; a.f = f;
    unsigned u = a.u;
    unsigned r = u + 0x7fffu + ((u >> 16) & 1u);   // RNE
    return (unsigned short)(r >> 16);
}

static __device__ __forceinline__ void load_lds_16(const void* gptr, void* lptr) {
    __builtin_amdgcn_global_load_lds(
        (const __attribute__((address_space(1))) unsigned int*)gptr,
        (__attribute__((address_space(3))) unsigned int*)lptr, 16, 0, 0);
}

// ---------------- merged prep: blocks [0,nx) convert x, blocks [nx,nx+4096) build W ----
// Slice-major dst: elem (row,k) -> rt=row>>8, ks=k>>4, rb=(row>>5)&7,
//                  lane=((k>>3)&1)*32+(row&31), j=k&7
//   index = (((rt*256 + ks)*8 + rb)*64 + lane)*8 + j
__global__ __launch_bounds__(256) void prep_all(
    const float* __restrict__ x,       // [4096][4096]
    const float* __restrict__ btt_r,   // [64][64][512]
    const float* __restrict__ btt_l,   // [64][512][64]
    unsigned short* __restrict__ xbt,  // tiled bf16
    unsigned short* __restrict__ Wtt,  // tiled bf16
    int nx)
{
    const int tid = threadIdx.x;
    if ((int)blockIdx.x < nx) {
        unsigned i = blockIdx.x * 256 + tid;
        int row = ((i >> 12) << 3) | (i & 7);
        int g   = (i >> 3) & 511;          // k-granule 0..511
        float4 v0 = *(const float4*)(x + (size_t)row * 4096 + g * 8);
        float4 v1 = *(const float4*)(x + (size_t)row * 4096 + g * 8 + 4);
        unsigned short o[8];
        o[0] = f2b(v0.x); o[1] = f2b(v0.y); o[2] = f2b(v0.z); o[3] = f2b(v0.w);
        o[4] = f2b(v1.x); o[5] = f2b(v1.y); o[6] = f2b(v1.z); o[7] = f2b(v1.w);
        int ks = g >> 1, half = g & 1;
        int rt = row >> 8, rb = (row >> 5) & 7, l31 = row & 31;
        size_t dst = ((((size_t)rt * 256 + ks) * 8 + rb) * 64 + half * 32 + l31) * 8;
        *(uint4*)(xbt + dst) = *(const uint4*)o;
        return;
    }
    // ---- W composition (per (m,n) block), slice-major dst
    __shared__ float Rs[64][8];
    __shared__ float Ls[8][64];
    const int wb = blockIdx.x - nx;
    const int m = wb >> 6, n = wb & 63;

    if (tid < 128) {
        int b = tid >> 1, rh = (tid & 1) * 4;
        float4 v = *(const float4*)(btt_r + (size_t)n * 32768 + (size_t)b * 512 + m * 8 + rh);
        *(float4*)&Rs[b][rh] = v;
    } else {
        int t2 = (tid - 128) * 4;
        float4 v = *(const float4*)(btt_l + (size_t)m * 32768 + n * 512 + t2);
        *(float4*)&(&Ls[0][0])[t2] = v;
    }
    __syncthreads();

    const int a  = tid >> 2;
    const int bg = (tid & 3) * 16;     // k-offset within n-block: 0,16,32,48
    float la[8];
    #pragma unroll
    for (int r = 0; r < 8; ++r) la[r] = Ls[r][a];

    unsigned short o[16];
    #pragma unroll
    for (int bb = 0; bb < 16; ++bb) {
        float acc = 0.f;
        #pragma unroll
        for (int r = 0; r < 8; ++r) acc += Rs[bg + bb][r] * la[r];
        o[bb] = f2b(acc);
    }
    int col = m * 64 + a;
    int ct = col >> 8, rb = (col >> 5) & 7, l31 = col & 31;
    int ks = n * 4 + (bg >> 4);        // global 16-k slice index
    size_t dst = ((((size_t)ct * 256 + ks) * 8 + rb) * 64 + l31) * 8;
    *(uint4*)(Wtt + dst)           = *(const uint4*)&o[0];   // k-octet half 0
    *(uint4*)(Wtt + dst + 32 * 8)  = *(const uint4*)&o[8];   // k-octet half 1
}

// ---------------- gemm: 256x256 tile, 8 waves (2Mx4N), 2-slice superphases ----------
__global__ __launch_bounds__(512, 2) void gemm_btt(
    const unsigned short* __restrict__ xbt,  // tiled
    const unsigned short* __restrict__ Wtt,  // tiled
    const float* __restrict__ bias,
    float* __restrict__ out)
{
    __shared__ unsigned short As[8][4096];   // 8 slots x 8KB
    __shared__ unsigned short Bs[8][4096];   // 128KB total -> 1 block/CU

    const int tid = threadIdx.x;
    // XCD rect swizzle: XCD x owns a 4rt x 8ct rectangle (bijective over 256 blocks)
    const int bid = blockIdx.x;
    const int jj = bid >> 3, xc = bid & 7;
    const int rt = (xc >> 1) * 4 + (jj >> 3);
    const int ct = (xc & 1) * 8 + (jj & 7);

    const int wid = tid >> 6, l = tid & 63;
    const int l31 = l & 31, half = l >> 5;
    const int wr = wid >> 2;                 // 0..1: 128-row half
    const int wc = wid & 3;                  // 0..3: 64-col quarter

    const unsigned short* xa = xbt + (size_t)rt * (256 * 4096);
    const unsigned short* wa = Wtt + (size_t)ct * (256 * 4096);

    const int offA0 = ((wr * 4 + 0) * 64 + l) * 8;
    const int offA1 = ((wr * 4 + 1) * 64 + l) * 8;
    const int offA2 = ((wr * 4 + 2) * 64 + l) * 8;
    const int offA3 = ((wr * 4 + 3) * 64 + l) * 8;
    const int offB0 = ((wc * 2 + 0) * 64 + l) * 8;
    const int offB1 = ((wc * 2 + 1) * 64 + l) * 8;

    f32x16 acc[4][2];
    #pragma unroll
    for (int i = 0; i < 4; ++i)
        #pragma unroll
        for (int j = 0; j < 2; ++j)
            #pragma unroll
            for (int r = 0; r < 16; ++r)
                acc[i][j][r] = 0.f;

    short8 fA0, fA1, fA2, fA3, fB0, fB1;     // slice-even fragments
    short8 gA0, gA1, gA2, gA3, gB0, gB1;     // slice-odd fragments

    #define STAGE(s, slot) do {                                               \
        load_lds_16(xa + (size_t)(s) * 4096 + tid * 8, &As[slot][tid * 8]);   \
        load_lds_16(wa + (size_t)(s) * 4096 + tid * 8, &Bs[slot][tid * 8]);   \
    } while (0)

    #define STAGE2(sa, sla, sb, slb) do {                                     \
        STAGE(sa, sla);                                                       \
        STAGE(sb, slb);                                                       \
    } while (0)

    #define NOSTAGE do { } while (0)

    #define READ6(pA0,pA1,pA2,pA3,pB0,pB1, slot) do {                         \
        const unsigned short* Ab = &As[slot][0];                              \
        const unsigned short* Bb = &Bs[slot][0];                              \
        pA0 = *(const short8*)(Ab + offA0);                                   \
        pA1 = *(const short8*)(Ab + offA1);                                   \
        pA2 = *(const short8*)(Ab + offA2);                                   \
        pA3 = *(const short8*)(Ab + offA3);                                   \
        pB0 = *(const short8*)(Bb + offB0);                                   \
        pB1 = *(const short8*)(Bb + offB1);                                   \
    } while (0)

    #define MFMA8(cA0,cA1,cA2,cA3,cB0,cB1) do {                               \
        acc[0][0] = __builtin_amdgcn_mfma_f32_32x32x16_bf16(cA0, cB0, acc[0][0], 0, 0, 0); \
        acc[0][1] = __builtin_amdgcn_mfma_f32_32x32x16_bf16(cA0, cB1, acc[0][1], 0, 0, 0); \
        acc[1][0] = __builtin_amdgcn_mfma_f32_32x32x16_bf16(cA1, cB0, acc[1][0], 0, 0, 0); \
        acc[1][1] = __builtin_amdgcn_mfma_f32_32x32x16_bf16(cA1, cB1, acc[1][1], 0, 0, 0); \
        acc[2][0] = __builtin_amdgcn_mfma_f32_32x32x16_bf16(cA2, cB0, acc[2][0], 0, 0, 0); \
        acc[2][1] = __builtin_amdgcn_mfma_f32_32x32x16_bf16(cA2, cB1, acc[2][1], 0, 0, 0); \
        acc[3][0] = __builtin_amdgcn_mfma_f32_32x32x16_bf16(cA3, cB0, acc[3][0], 0, 0, 0); \
        acc[3][1] = __builtin_amdgcn_mfma_f32_32x32x16_bf16(cA3, cB1, acc[3][1], 0, 0, 0); \
    } while (0)

    // superphase: vmcnt ; barrier ; stage next pair ; read 12 ; 16 MFMA
    #define SUPER(e, STAGE_STMT, VMSTR) do {                                  \
        asm volatile(VMSTR ::: "memory");                                     \
        __builtin_amdgcn_s_barrier();                                         \
        asm volatile("" ::: "memory");                                        \
        STAGE_STMT;                                                           \
        READ6(fA0,fA1,fA2,fA3,fB0,fB1, (e));                                  \
        READ6(gA0,gA1,gA2,gA3,gB0,gB1, (e) + 1);                              \
        __builtin_amdgcn_s_setprio(1);                                        \
        MFMA8(fA0,fA1,fA2,fA3,fB0,fB1);                                       \
        MFMA8(gA0,gA1,gA2,gA3,gB0,gB1);                                       \
        __builtin_amdgcn_s_setprio(0);                                        \
    } while (0)

    // prologue: stage slices 0..5 into slots 0..5 (12 loads/wave in flight)
    STAGE(0, 0); STAGE(1, 1); STAGE(2, 2); STAGE(3, 3); STAGE(4, 4); STAGE(5, 5);

    // main: superphases p = 0..123 (31 x 4); sp p consumes slices 2p,2p+1,
    // stages slices 2p+6,2p+7 into slots (2p+6)&7,(2p+7)&7
    #pragma unroll 1
    for (int it2 = 0; it2 < 31; ++it2) {
        const int s8 = it2 * 8;
        SUPER(0, STAGE2(s8 + 6,  6, s8 + 7,  7), "s_waitcnt vmcnt(8)");
        SUPER(2, STAGE2(s8 + 8,  0, s8 + 9,  1), "s_waitcnt vmcnt(8)");
        SUPER(4, STAGE2(s8 + 10, 2, s8 + 11, 3), "s_waitcnt vmcnt(8)");
        SUPER(6, STAGE2(s8 + 12, 4, s8 + 13, 5), "s_waitcnt vmcnt(8)");
    }
    // tail: sps 124..127 (slices 248..255); last stage at sp 124; drain 8->8->4->0
    SUPER(0, STAGE2(254, 6, 255, 7), "s_waitcnt vmcnt(8)");  // sp 124
    SUPER(2, NOSTAGE,                "s_waitcnt vmcnt(8)");  // sp 125
    SUPER(4, NOSTAGE,                "s_waitcnt vmcnt(4)");  // sp 126
    SUPER(6, NOSTAGE,                "s_waitcnt vmcnt(0)");  // sp 127

    // epilogue: C/D layout col=lane&31, row=(r&3)+8*(r>>2)+4*half  [m74/m101]
    const int rowTileBase = rt * 256 + wr * 128;
    const int colTileBase = ct * 256 + wc * 64;
    #pragma unroll
    for (int jn = 0; jn < 2; ++jn) {
        const int col = colTileBase + jn * 32 + l31;
        const float bv = bias[col];
        #pragma unroll
        for (int i = 0; i < 4; ++i) {
            const int rbase = rowTileBase + i * 32 + 4 * half;
            #pragma unroll
            for (int r = 0; r < 16; ++r) {
                int row = rbase + (r & 3) + 8 * (r >> 2);
                out[(size_t)row * 4096 + col] = acc[i][jn][r] + bv;
            }
        }
    }
    #undef STAGE
    #undef STAGE2
    #undef NOSTAGE
    #undef READ6
    #undef MFMA8
    #undef SUPER
}

extern "C" void kernel_launch(void* const* d_in, const int* in_sizes, int n_in,
                              void* d_out, int out_size, void* d_ws, size_t ws_size,
                              hipStream_t stream) {
    const float* x    = (const float*)d_in[0];
    const float* r    = (const float*)d_in[1];
    const float* l    = (const float*)d_in[2];
    const float* bias = (const float*)d_in[3];
    float* out = (float*)d_out;

    unsigned short* xbt = (unsigned short*)d_ws;                       // 32 MB
    unsigned short* Wtt = (unsigned short*)d_ws + (size_t)4096 * 4096; // 32 MB

    const int rows = in_sizes[0] / 4096;        // 4096
    const int nx = rows * 4096 / 8 / 256;       // 8192 x-conversion blocks

    prep_all<<<dim3(nx + 4096), dim3(256), 0, stream>>>(x, r, l, xbt, Wtt, nx);
    gemm_btt<<<dim3((rows / 256) * 16), dim3(512), 0, stream>>>(xbt, Wtt, bias, out);
}

// Round 7
// 260.942 us; speedup vs baseline: 1.1361x; 1.0677x over previous
//
#include <hip/hip_runtime.h>

// BTT(4096->4096, m=n=a=b=64, rank=8) == dense 4096x4096 matmul:
//   W[n*64+b][m*64+a] = sum_r R[n,b,m*8+r] * L[m,n*8+r,a];  out = x @ W + bias
// R10: prep split + coalesced rewrite; gemm = R9b unchanged (132 µs verified).
//   conv_x: 64x64 block, LDS transpose, 1-KB contiguous dst chunks.
//   prep_w: per-wave 1-KB contiguous dst chunks (was 16-B scatter).
// Slice-major layout (unchanged): elem (row,k) -> rt=row>>8, ks=k>>4,
//   rb=(row>>5)&7, lane=((k>>3)&1)*32+(row&31), j=k&7
//   index = (((rt*256 + ks)*8 + rb)*64 + lane)*8 + j

typedef float f32x16 __attribute__((ext_vector_type(16)));
typedef short short8 __attribute__((ext_vector_type(8)));

static __device__ __forceinline__ unsigned short f2b(float f) {
    union { float f; unsigned u; } a; a.f = f;
    unsigned u = a.u;
    unsigned r = u + 0x7fffu + ((u >> 16) & 1u);   // RNE
    return (unsigned short)(r >> 16);
}

static __device__ __forceinline__ void load_lds_16(const void* gptr, void* lptr) {
    __builtin_amdgcn_global_load_lds(
        (const __attribute__((address_space(1))) unsigned int*)gptr,
        (__attribute__((address_space(3))) unsigned int*)lptr, 16, 0, 0);
}

// ---------------- x conversion: fully coalesced via LDS transpose ----------------
// Block handles 64 rows x 64 k. Read: 4 float4/thread, 256-B runs per row.
// LDS: chunk c = ks_local*2 + rb_local, [c][lane][8] bf16 (lane = half*32 + row&31).
// Write: 8 chunks x 1 KB contiguous, 64 lanes x uint4 each.
__global__ __launch_bounds__(256) void conv_x(
    const float* __restrict__ x, unsigned short* __restrict__ xbt, int rows)
{
    __shared__ unsigned short Lx[8][64][8];   // 8 KB
    const int tid = threadIdx.x;
    const int bx = blockIdx.x;
    const int kblk = bx & 63;                 // 64-k block
    const int rowblk = bx >> 6;               // 64-row block

    const int r6 = tid >> 2, kq = tid & 3;    // row-in-block, 16-k quarter
    const int row = rowblk * 64 + r6;
    const float* src = x + (size_t)row * 4096 + kblk * 64 + kq * 16;
    float4 v0 = *(const float4*)(src + 0);
    float4 v1 = *(const float4*)(src + 4);
    float4 v2 = *(const float4*)(src + 8);
    float4 v3 = *(const float4*)(src + 12);
    unsigned short o[16];
    o[0]  = f2b(v0.x); o[1]  = f2b(v0.y); o[2]  = f2b(v0.z); o[3]  = f2b(v0.w);
    o[4]  = f2b(v1.x); o[5]  = f2b(v1.y); o[6]  = f2b(v1.z); o[7]  = f2b(v1.w);
    o[8]  = f2b(v2.x); o[9]  = f2b(v2.y); o[10] = f2b(v2.z); o[11] = f2b(v2.w);
    o[12] = f2b(v3.x); o[13] = f2b(v3.y); o[14] = f2b(v3.z); o[15] = f2b(v3.w);
    const int rb_l = r6 >> 5, l31 = r6 & 31;
    const int c = kq * 2 + rb_l;
    *(uint4*)&Lx[c][0 * 32 + l31][0] = *(const uint4*)&o[0];   // k-octet half 0
    *(uint4*)&Lx[c][1 * 32 + l31][0] = *(const uint4*)&o[8];   // k-octet half 1
    __syncthreads();

    const int lane = tid & 63;
    const int cc0 = tid >> 6;                 // wave id 0..3
    const int rt = rowblk >> 2;
    #pragma unroll
    for (int p = 0; p < 2; ++p) {
        const int cc = cc0 + p * 4;           // chunk = ks_local*2 + rb_local
        const int ksl = cc >> 1, rbl = cc & 1;
        const int ks = kblk * 4 + ksl;
        const int rb = (rowblk & 3) * 2 + rbl;
        size_t dst = ((((size_t)rt * 256 + ks) * 8 + rb) * 64 + lane) * 8;
        *(uint4*)(xbt + dst) = *(const uint4*)&Lx[cc][lane][0];
    }
}

// ---------------- W composition: per-wave 1-KB contiguous chunks ----------------
// Block = (m,n). Wave w, pass p handles chunk c = p*4+w = rb*4 + ks_local.
// Lane l: col = m*64 + rb*32 + (l&31); b_j = ks_local*16 + (l>>5)*8 + j.
__global__ __launch_bounds__(256) void prep_w(
    const float* __restrict__ btt_r,   // [64][64][512]
    const float* __restrict__ btt_l,   // [64][512][64]
    unsigned short* __restrict__ Wtt)
{
    __shared__ float Rs[64][8];
    __shared__ float Ls[8][64];
    const int tid = threadIdx.x;
    const int wb = blockIdx.x;
    const int m = wb >> 6, n = wb & 63;

    if (tid < 128) {
        int b = tid >> 1, rh = (tid & 1) * 4;
        float4 v = *(const float4*)(btt_r + (size_t)n * 32768 + (size_t)b * 512 + m * 8 + rh);
        *(float4*)&Rs[b][rh] = v;
    } else {
        int t2 = (tid - 128) * 4;
        float4 v = *(const float4*)(btt_l + (size_t)m * 32768 + n * 512 + t2);
        *(float4*)&(&Ls[0][0])[t2] = v;
    }
    __syncthreads();

    const int lane = tid & 63;
    const int lc = lane & 31, half = lane >> 5;
    const int ct = m >> 2;
    #pragma unroll
    for (int p = 0; p < 2; ++p) {
        const int c = p * 4 + (tid >> 6);     // c = rb*4 + ks_local (wave-uniform)
        const int rb = c >> 2, ksl = c & 3;
        const int col6 = rb * 32 + lc;        // col within m-block
        float la[8];
        #pragma unroll
        for (int r = 0; r < 8; ++r) la[r] = Ls[r][col6];
        const int b0 = ksl * 16 + half * 8;
        unsigned short o[8];
        #pragma unroll
        for (int j = 0; j < 8; ++j) {
            float4 rv0 = *(const float4*)&Rs[b0 + j][0];
            float4 rv1 = *(const float4*)&Rs[b0 + j][4];
            float acc = rv0.x * la[0];
            acc += rv0.y * la[1]; acc += rv0.z * la[2]; acc += rv0.w * la[3];
            acc += rv1.x * la[4]; acc += rv1.y * la[5]; acc += rv1.z * la[6];
            acc += rv1.w * la[7];
            o[j] = f2b(acc);
        }
        const int ks = n * 4 + ksl;
        const int rbg = (m & 3) * 2 + rb;
        size_t dst = ((((size_t)ct * 256 + ks) * 8 + rbg) * 64 + lane) * 8;
        *(uint4*)(Wtt + dst) = *(const uint4*)&o[0];
    }
}

// ---------------- gemm: 256x256 tile, 8 waves (2Mx4N), 2-slice superphases ----------
// (unchanged from R9b: vmcnt(8) counted waits, 1 barrier / 32 k, setprio, 0-conflict)
__global__ __launch_bounds__(512, 2) void gemm_btt(
    const unsigned short* __restrict__ xbt,  // tiled
    const unsigned short* __restrict__ Wtt,  // tiled
    const float* __restrict__ bias,
    float* __restrict__ out)
{
    __shared__ unsigned short As[8][4096];   // 8 slots x 8KB
    __shared__ unsigned short Bs[8][4096];   // 128KB total -> 1 block/CU

    const int tid = threadIdx.x;
    // XCD rect swizzle: XCD x owns a 4rt x 8ct rectangle (bijective over 256 blocks)
    const int bid = blockIdx.x;
    const int jj = bid >> 3, xc = bid & 7;
    const int rt = (xc >> 1) * 4 + (jj >> 3);
    const int ct = (xc & 1) * 8 + (jj & 7);

    const int wid = tid >> 6, l = tid & 63;
    const int l31 = l & 31, half = l >> 5;
    const int wr = wid >> 2;                 // 0..1: 128-row half
    const int wc = wid & 3;                  // 0..3: 64-col quarter

    const unsigned short* xa = xbt + (size_t)rt * (256 * 4096);
    const unsigned short* wa = Wtt + (size_t)ct * (256 * 4096);

    const int offA0 = ((wr * 4 + 0) * 64 + l) * 8;
    const int offA1 = ((wr * 4 + 1) * 64 + l) * 8;
    const int offA2 = ((wr * 4 + 2) * 64 + l) * 8;
    const int offA3 = ((wr * 4 + 3) * 64 + l) * 8;
    const int offB0 = ((wc * 2 + 0) * 64 + l) * 8;
    const int offB1 = ((wc * 2 + 1) * 64 + l) * 8;

    f32x16 acc[4][2];
    #pragma unroll
    for (int i = 0; i < 4; ++i)
        #pragma unroll
        for (int j = 0; j < 2; ++j)
            #pragma unroll
            for (int r = 0; r < 16; ++r)
                acc[i][j][r] = 0.f;

    short8 fA0, fA1, fA2, fA3, fB0, fB1;     // slice-even fragments
    short8 gA0, gA1, gA2, gA3, gB0, gB1;     // slice-odd fragments

    #define STAGE(s, slot) do {                                               \
        load_lds_16(xa + (size_t)(s) * 4096 + tid * 8, &As[slot][tid * 8]);   \
        load_lds_16(wa + (size_t)(s) * 4096 + tid * 8, &Bs[slot][tid * 8]);   \
    } while (0)

    #define STAGE2(sa, sla, sb, slb) do {                                     \
        STAGE(sa, sla);                                                       \
        STAGE(sb, slb);                                                       \
    } while (0)

    #define NOSTAGE do { } while (0)

    #define READ6(pA0,pA1,pA2,pA3,pB0,pB1, slot) do {                         \
        const unsigned short* Ab = &As[slot][0];                              \
        const unsigned short* Bb = &Bs[slot][0];                              \
        pA0 = *(const short8*)(Ab + offA0);                                   \
        pA1 = *(const short8*)(Ab + offA1);                                   \
        pA2 = *(const short8*)(Ab + offA2);                                   \
        pA3 = *(const short8*)(Ab + offA3);                                   \
        pB0 = *(const short8*)(Bb + offB0);                                   \
        pB1 = *(const short8*)(Bb + offB1);                                   \
    } while (0)

    #define MFMA8(cA0,cA1,cA2,cA3,cB0,cB1) do {                               \
        acc[0][0] = __builtin_amdgcn_mfma_f32_32x32x16_bf16(cA0, cB0, acc[0][0], 0, 0, 0); \
        acc[0][1] = __builtin_amdgcn_mfma_f32_32x32x16_bf16(cA0, cB1, acc[0][1], 0, 0, 0); \
        acc[1][0] = __builtin_amdgcn_mfma_f32_32x32x16_bf16(cA1, cB0, acc[1][0], 0, 0, 0); \
        acc[1][1] = __builtin_amdgcn_mfma_f32_32x32x16_bf16(cA1, cB1, acc[1][1], 0, 0, 0); \
        acc[2][0] = __builtin_amdgcn_mfma_f32_32x32x16_bf16(cA2, cB0, acc[2][0], 0, 0, 0); \
        acc[2][1] = __builtin_amdgcn_mfma_f32_32x32x16_bf16(cA2, cB1, acc[2][1], 0, 0, 0); \
        acc[3][0] = __builtin_amdgcn_mfma_f32_32x32x16_bf16(cA3, cB0, acc[3][0], 0, 0, 0); \
        acc[3][1] = __builtin_amdgcn_mfma_f32_32x32x16_bf16(cA3, cB1, acc[3][1], 0, 0, 0); \
    } while (0)

    // superphase: vmcnt ; barrier ; stage next pair ; read 12 ; 16 MFMA
    #define SUPER(e, STAGE_STMT, VMSTR) do {                                  \
        asm volatile(VMSTR ::: "memory");                                     \
        __builtin_amdgcn_s_barrier();                                         \
        asm volatile("" ::: "memory");                                        \
        STAGE_STMT;                                                           \
        READ6(fA0,fA1,fA2,fA3,fB0,fB1, (e));                                  \
        READ6(gA0,gA1,gA2,gA3,gB0,gB1, (e) + 1);                              \
        __builtin_amdgcn_s_setprio(1);                                        \
        MFMA8(fA0,fA1,fA2,fA3,fB0,fB1);                                       \
        MFMA8(gA0,gA1,gA2,gA3,gB0,gB1);                                       \
        __builtin_amdgcn_s_setprio(0);                                        \
    } while (0)

    // prologue: stage slices 0..5 into slots 0..5 (12 loads/wave in flight)
    STAGE(0, 0); STAGE(1, 1); STAGE(2, 2); STAGE(3, 3); STAGE(4, 4); STAGE(5, 5);

    // main: superphases p = 0..123 (31 x 4); sp p consumes slices 2p,2p+1,
    // stages slices 2p+6,2p+7 into slots (2p+6)&7,(2p+7)&7
    #pragma unroll 1
    for (int it2 = 0; it2 < 31; ++it2) {
        const int s8 = it2 * 8;
        SUPER(0, STAGE2(s8 + 6,  6, s8 + 7,  7), "s_waitcnt vmcnt(8)");
        SUPER(2, STAGE2(s8 + 8,  0, s8 + 9,  1), "s_waitcnt vmcnt(8)");
        SUPER(4, STAGE2(s8 + 10, 2, s8 + 11, 3), "s_waitcnt vmcnt(8)");
        SUPER(6, STAGE2(s8 + 12, 4, s8 + 13, 5), "s_waitcnt vmcnt(8)");
    }
    // tail: sps 124..127 (slices 248..255); last stage at sp 124; drain 8->8->4->0
    SUPER(0, STAGE2(254, 6, 255, 7), "s_waitcnt vmcnt(8)");  // sp 124
    SUPER(2, NOSTAGE,                "s_waitcnt vmcnt(8)");  // sp 125
    SUPER(4, NOSTAGE,                "s_waitcnt vmcnt(4)");  // sp 126
    SUPER(6, NOSTAGE,                "s_waitcnt vmcnt(0)");  // sp 127

    // epilogue: C/D layout col=lane&31, row=(r&3)+8*(r>>2)+4*half  [m74/m101]
    const int rowTileBase = rt * 256 + wr * 128;
    const int colTileBase = ct * 256 + wc * 64;
    #pragma unroll
    for (int jn = 0; jn < 2; ++jn) {
        const int col = colTileBase + jn * 32 + l31;
        const float bv = bias[col];
        #pragma unroll
        for (int i = 0; i < 4; ++i) {
            const int rbase = rowTileBase + i * 32 + 4 * half;
            #pragma unroll
            for (int r = 0; r < 16; ++r) {
                int row = rbase + (r & 3) + 8 * (r >> 2);
                out[(size_t)row * 4096 + col] = acc[i][jn][r] + bv;
            }
        }
    }
    #undef STAGE
    #undef STAGE2
    #undef NOSTAGE
    #undef READ6
    #undef MFMA8
    #undef SUPER
}

extern "C" void kernel_launch(void* const* d_in, const int* in_sizes, int n_in,
                              void* d_out, int out_size, void* d_ws, size_t ws_size,
                              hipStream_t stream) {
    const float* x    = (const float*)d_in[0];
    const float* r    = (const float*)d_in[1];
    const float* l    = (const float*)d_in[2];
    const float* bias = (const float*)d_in[3];
    float* out = (float*)d_out;

    unsigned short* xbt = (unsigned short*)d_ws;                       // 32 MB
    unsigned short* Wtt = (unsigned short*)d_ws + (size_t)4096 * 4096; // 32 MB

    const int rows = in_sizes[0] / 4096;        // 4096

    conv_x<<<dim3((rows >> 6) * 64), dim3(256), 0, stream>>>(x, xbt, rows);
    prep_w<<<dim3(4096), dim3(256), 0, stream>>>(r, l, Wtt);
    gemm_btt<<<dim3((rows / 256) * 16), dim3(512), 0, stream>>>(xbt, Wtt, bias, out);
}